// Round 1
// baseline (311.808 us; speedup 1.0000x reference)
//
#include <hip/hip_runtime.h>

typedef __bf16 bf16;
typedef __attribute__((ext_vector_type(4))) __bf16 bf16x4;
typedef __attribute__((ext_vector_type(8))) __bf16 bf16x8;
typedef __attribute__((ext_vector_type(4))) float f32x4;

#define MFMA(A,B,C) __builtin_amdgcn_mfma_f32_16x16x32_bf16(A,B,C,0,0,0)

#define SEQ 2048
#define EMB 512
#define HD  64
#define SCALE 22.627416997969522f  // sqrt(512): scores are divided by E^-0.5
// Online-softmax seed: not -inf (fast-math folds inf constants to poison).
#define NEG_SEED -3.0e4f

// ---------------------------------------------------------------------------
// QKV projection: fp32 in, hi/lo split MFMA. XCD-stripe swizzle: each XCD
// (linear%8) owns a contiguous 1024-row m-stripe; within an XCD the m-block
// varies fastest -> per-XCD L2 working set = A-slice 2.1MB + W 3MB (resident).
// ---------------------------------------------------------------------------
__global__ __launch_bounds__(256)
void gemm_qkv(const float* __restrict__ A, const float* __restrict__ Bm,
              const float* __restrict__ bias,
              bf16* __restrict__ Qh, bf16* __restrict__ Ql,
              bf16* __restrict__ Kh, bf16* __restrict__ Kl,
              bf16* __restrict__ Vt) {
  __shared__ __align__(16) bf16 Ah[64][72], Al[64][72];
  __shared__ __align__(16) bf16 Bh[64][72], Bl[64][72];
  const int tid  = threadIdx.x;
  const int lane = tid & 63, wave = tid >> 6;
  // XCD-stripe swizzle (3072 blocks = 8 stripes x 16 m-blocks x 24 n-tiles)
  const int lin = blockIdx.x + gridDim.x * blockIdx.y;
  const int xcd = lin & 7;
  const int w_  = lin >> 3;                  // 0..383
  const int m0 = ((w_ & 15) + xcd * 16) * 64;
  const int n0 = (w_ >> 4) * 64;
  const int wm = (wave >> 1) * 32, wn = (wave & 1) * 32;
  const int c = lane & 15, quad = lane >> 4;
  const int fr = tid >> 4, fc = (tid & 15) * 4;

  const f32x4 zero = {0.f, 0.f, 0.f, 0.f};
  f32x4 acc[2][2];
  acc[0][0] = zero; acc[0][1] = zero; acc[1][0] = zero; acc[1][1] = zero;

  for (int k0 = 0; k0 < 512; k0 += 64) {
#pragma unroll
    for (int rr = 0; rr < 4; ++rr) {
      const int row = rr * 16 + fr;
      f32x4 av = *(const f32x4*)&A [(size_t)(m0 + row) * 512 + k0 + fc];
      f32x4 bv = *(const f32x4*)&Bm[(size_t)(n0 + row) * 512 + k0 + fc];
      bf16x4 ah, al, bh, bl;
#pragma unroll
      for (int j = 0; j < 4; ++j) {
        bf16 h = (bf16)av[j]; ah[j] = h; al[j] = (bf16)(av[j] - (float)h);
        bf16 g = (bf16)bv[j]; bh[j] = g; bl[j] = (bf16)(bv[j] - (float)g);
      }
      *(bf16x4*)&Ah[row][fc] = ah; *(bf16x4*)&Al[row][fc] = al;
      *(bf16x4*)&Bh[row][fc] = bh; *(bf16x4*)&Bl[row][fc] = bl;
    }
    __syncthreads();
#pragma unroll
    for (int ks = 0; ks < 64; ks += 32) {
      bf16x8 ah0 = *(bf16x8*)&Ah[wm + c     ][ks + quad * 8];
      bf16x8 ah1 = *(bf16x8*)&Ah[wm + 16 + c][ks + quad * 8];
      bf16x8 al0 = *(bf16x8*)&Al[wm + c     ][ks + quad * 8];
      bf16x8 al1 = *(bf16x8*)&Al[wm + 16 + c][ks + quad * 8];
      bf16x8 bh0 = *(bf16x8*)&Bh[wn + c     ][ks + quad * 8];
      bf16x8 bh1 = *(bf16x8*)&Bh[wn + 16 + c][ks + quad * 8];
      bf16x8 bl0 = *(bf16x8*)&Bl[wn + c     ][ks + quad * 8];
      bf16x8 bl1 = *(bf16x8*)&Bl[wn + 16 + c][ks + quad * 8];
      acc[0][0] = MFMA(ah0, bh0, acc[0][0]);
      acc[0][0] = MFMA(al0, bh0, acc[0][0]);
      acc[0][0] = MFMA(ah0, bl0, acc[0][0]);
      acc[0][1] = MFMA(ah0, bh1, acc[0][1]);
      acc[0][1] = MFMA(al0, bh1, acc[0][1]);
      acc[0][1] = MFMA(ah0, bl1, acc[0][1]);
      acc[1][0] = MFMA(ah1, bh0, acc[1][0]);
      acc[1][0] = MFMA(al1, bh0, acc[1][0]);
      acc[1][0] = MFMA(ah1, bl0, acc[1][0]);
      acc[1][1] = MFMA(ah1, bh1, acc[1][1]);
      acc[1][1] = MFMA(al1, bh1, acc[1][1]);
      acc[1][1] = MFMA(ah1, bl1, acc[1][1]);
    }
    __syncthreads();
  }

#pragma unroll
  for (int mt = 0; mt < 2; ++mt) {
#pragma unroll
    for (int nt = 0; nt < 2; ++nt) {
      const int n = n0 + wn + nt * 16 + c;
      const float bv = bias[n];
#pragma unroll
      for (int r = 0; r < 4; ++r) {
        const int m = m0 + wm + mt * 16 + quad * 4 + r;
        float v = acc[mt][nt][r] + bv;
        const int h = n / 192, t = n % 192;
        const size_t bh = (size_t)((m >> 11) * 8 + h);
        const int s = m & 2047;
        if (t < 64) {
          float q = v * SCALE;
          bf16 hi = (bf16)q;
          float lo = q - (float)hi;
          size_t idx = (bh * SEQ + s) * HD + t;
          Qh[idx] = hi; Ql[idx] = (bf16)lo;
        } else if (t < 128) {
          bf16 hi = (bf16)v;
          float lo = v - (float)hi;
          size_t idx = (bh * SEQ + s) * HD + (t - 64);
          Kh[idx] = hi; Kl[idx] = (bf16)lo;
        } else {
          Vt[(bh * HD + (t - 128)) * SEQ + s] = (bf16)v;
        }
      }
    }
  }
}

// ---------------------------------------------------------------------------
// Output projection: fp32 out. Same XCD-stripe swizzle (1024 blocks).
// ---------------------------------------------------------------------------
__global__ __launch_bounds__(256)
void gemm_out(const bf16* __restrict__ A, const float* __restrict__ Bm,
              const float* __restrict__ bias, float* __restrict__ C) {
  __shared__ __align__(16) bf16 As[64][72];
  __shared__ __align__(16) bf16 Bs[64][72];
  const int tid  = threadIdx.x;
  const int lane = tid & 63, wave = tid >> 6;
  const int lin = blockIdx.x + gridDim.x * blockIdx.y;
  const int xcd = lin & 7;
  const int w_  = lin >> 3;                  // 0..127
  const int m0 = ((w_ & 15) + xcd * 16) * 64;
  const int n0 = (w_ >> 4) * 64;
  const int wm = (wave >> 1) * 32, wn = (wave & 1) * 32;
  const int c = lane & 15, quad = lane >> 4;
  const int lr = tid >> 3, lc = (tid & 7) * 8;
  const int fr = tid >> 4, fc = (tid & 15) * 4;

  const f32x4 zero = {0.f, 0.f, 0.f, 0.f};
  f32x4 acc[2][2];
  acc[0][0] = zero; acc[0][1] = zero; acc[1][0] = zero; acc[1][1] = zero;

  for (int k0 = 0; k0 < 512; k0 += 64) {
    *(bf16x8*)&As[lr][lc]      = *(const bf16x8*)&A[(size_t)(m0 + lr     ) * 512 + k0 + lc];
    *(bf16x8*)&As[lr + 32][lc] = *(const bf16x8*)&A[(size_t)(m0 + lr + 32) * 512 + k0 + lc];
#pragma unroll
    for (int rr = 0; rr < 4; ++rr) {
      const int row = rr * 16 + fr;
      f32x4 bv = *(const f32x4*)&Bm[(size_t)(n0 + row) * 512 + k0 + fc];
      bf16x4 bb;
#pragma unroll
      for (int j = 0; j < 4; ++j) bb[j] = (bf16)bv[j];
      *(bf16x4*)&Bs[row][fc] = bb;
    }
    __syncthreads();
#pragma unroll
    for (int ks = 0; ks < 64; ks += 32) {
      bf16x8 a0 = *(bf16x8*)&As[wm + c     ][ks + quad * 8];
      bf16x8 a1 = *(bf16x8*)&As[wm + 16 + c][ks + quad * 8];
      bf16x8 b0 = *(bf16x8*)&Bs[wn + c     ][ks + quad * 8];
      bf16x8 b1 = *(bf16x8*)&Bs[wn + 16 + c][ks + quad * 8];
      acc[0][0] = MFMA(a0, b0, acc[0][0]);
      acc[0][1] = MFMA(a0, b1, acc[0][1]);
      acc[1][0] = MFMA(a1, b0, acc[1][0]);
      acc[1][1] = MFMA(a1, b1, acc[1][1]);
    }
    __syncthreads();
  }

#pragma unroll
  for (int mt = 0; mt < 2; ++mt) {
#pragma unroll
    for (int nt = 0; nt < 2; ++nt) {
      const int n = n0 + wn + nt * 16 + c;
      const float bv = bias[n];
#pragma unroll
      for (int r = 0; r < 4; ++r) {
        const int m = m0 + wm + mt * 16 + quad * 4 + r;
        C[(size_t)m * 512 + n] = acc[mt][nt][r] + bv;
      }
    }
  }
}

// ---------------------------------------------------------------------------
// Per-head V column sums: Vtot[bh][d] = sum_s Vt[bh][d][s].
// One wave per (bh,d) row; 8MB read, L2/L3-resident, ~3us.
// ---------------------------------------------------------------------------
__global__ __launch_bounds__(256)
void vsum_kernel(const bf16* __restrict__ Vt, float* __restrict__ Vs) {
  const int row  = blockIdx.x * 4 + (threadIdx.x >> 6);   // 0..2047
  const int lane = threadIdx.x & 63;
  const bf16* p = Vt + (size_t)row * SEQ;
  float s = 0.f;
#pragma unroll
  for (int it = 0; it < 4; ++it) {
    bf16x8 v = *(const bf16x8*)&p[(it * 64 + lane) * 8];
#pragma unroll
    for (int j = 0; j < 8; ++j) s += (float)v[j];
  }
#pragma unroll
  for (int off = 1; off < 64; off <<= 1) s += __shfl_xor(s, off, 64);
  if (lane == 0) Vs[row] = s;
}

// ---------------------------------------------------------------------------
// Attention, double softmax, S^T orientation + Vtot DECOMPOSITION:
//   O = sum_k t_k V_k = Vtot + sum_k (t_k - 1) V_k,   l2 = 2048 + sum (t_k-1)
// where t = exp(attn1). For keys with chunk-max < m-18 we have t == 1.0f
// exactly (a1 < e^-18 < 2^-24), i.e. t-1 == 0: those chunks contribute
// NOTHING beyond Vtot. Pass 1 (unchanged math: exact online m, l1) also
// records the per-query chunk max into LDS. Pass 2 then visits ONLY chunks
// where some query in the wave is active (~15-20 of 64): barrier-free, K/V
// fragments read straight from global (L2/L3-hit), t-1 in bf16 (strictly
// more accurate than t in bf16). No V staging, no pass-2 K staging, no
// pass-2 barriers, ~70% of pass-2 MFMAs gone.
// ---------------------------------------------------------------------------
__global__ __launch_bounds__(256, 4)
void attn_kernel(const bf16* __restrict__ Qh, const bf16* __restrict__ Ql,
                 const bf16* __restrict__ Kh, const bf16* __restrict__ Kl,
                 const bf16* __restrict__ Vt, const float* __restrict__ Vs,
                 bf16* __restrict__ O) {
  __shared__ __align__(16) bf16 KhS[2][32][64];  // [key][d], chunk^=(row&7)
  __shared__ __align__(16) bf16 KlS[2][32][64];
  __shared__ __align__(16) bf16 tls[4][16][40];  // per-wave t^T[q][key], +8 pad
  __shared__ float cms[4][64][16];               // per-wave per-chunk per-query max
  const int tid  = threadIdx.x;
  const int lane = tid & 63, wave = tid >> 6;
  const int c = lane & 15, quad = lane >> 4;
  const int bh = blockIdx.x;
  const int q0 = blockIdx.y * 64 + wave * 16;
  const size_t hoff = (size_t)bh * SEQ * HD;
  const bf16* qh_p = Qh + hoff;
  const bf16* ql_p = Ql + hoff;
  const bf16* kh_p = Kh + hoff;
  const bf16* kl_p = Kl + hoff;
  const bf16* vt_p = Vt + hoff;                  // [HD][SEQ]
  const f32x4 zero = {0.f, 0.f, 0.f, 0.f};

  const int krow = tid >> 3;
  const int kcol = (tid & 7) * 8;
  const int kphy = ((tid & 7) ^ (krow & 7)) * 8;
  const int pc0 = ((0 + quad) ^ (c & 7)) * 8;
  const int pc1 = ((4 + quad) ^ (c & 7)) * 8;

  bf16x8 qf[2], qlf[2];
#pragma unroll
  for (int t = 0; t < 2; ++t) {
    size_t off = (size_t)(q0 + c) * HD + t * 32 + quad * 8;
    qf[t]  = *(const bf16x8*)&qh_p[off];
    qlf[t] = *(const bf16x8*)&ql_p[off];
  }

  float mr = NEG_SEED, l1 = 0.f;

  // ================= pass 1: online (m, L1), sparse; record chunk maxes ====
  bf16x8 ph, pl;
  ph = *(const bf16x8*)&kh_p[(size_t)krow * HD + kcol];
  pl = *(const bf16x8*)&kl_p[(size_t)krow * HD + kcol];
  *(bf16x8*)&KhS[0][krow][kphy] = ph;
  *(bf16x8*)&KlS[0][krow][kphy] = pl;
  __syncthreads();
  int buf = 0;
  for (int ch = 0; ch < 64; ++ch) {
    if (ch < 63) {
      const size_t k0 = (size_t)(ch + 1) * 32;
      ph = *(const bf16x8*)&kh_p[(k0 + krow) * HD + kcol];
      pl = *(const bf16x8*)&kl_p[(k0 + krow) * HD + kcol];
    }
    float cmc = -3.4e38f;
#pragma unroll
    for (int kt = 0; kt < 2; ++kt) {
      const int row = kt * 16 + c;
      bf16x8 kh0 = *(bf16x8*)&KhS[buf][row][pc0];
      bf16x8 kl0 = *(bf16x8*)&KlS[buf][row][pc0];
      bf16x8 kh1 = *(bf16x8*)&KhS[buf][row][pc1];
      bf16x8 kl1 = *(bf16x8*)&KlS[buf][row][pc1];
      f32x4 sc = zero;
      sc = MFMA(kh0, qf[0],  sc);
      sc = MFMA(kh0, qlf[0], sc);
      sc = MFMA(kl0, qf[0],  sc);
      sc = MFMA(kh1, qf[1],  sc);
      sc = MFMA(kh1, qlf[1], sc);
      sc = MFMA(kl1, qf[1],  sc);
      float cm = fmaxf(fmaxf(sc[0], sc[1]), fmaxf(sc[2], sc[3]));
      cmc = fmaxf(cmc, cm);
      if (cm > mr - 90.f) {   // else: all exp(s-m) underflow to 0 exactly
        float nm = fmaxf(mr, cm);
        l1 = l1 * __expf(mr - nm) + __expf(sc[0] - nm) + __expf(sc[1] - nm)
                                  + __expf(sc[2] - nm) + __expf(sc[3] - nm);
        mr = nm;
      }
    }
    // per-query chunk max (reduce across the 4 quad lanes of query c)
    cmc = fmaxf(cmc, __shfl_xor(cmc, 16, 64));
    cmc = fmaxf(cmc, __shfl_xor(cmc, 32, 64));
    if (quad == 0) cms[wave][ch][c] = cmc;
    if (ch < 63) {
      *(bf16x8*)&KhS[buf ^ 1][krow][kphy] = ph;
      *(bf16x8*)&KlS[buf ^ 1][krow][kphy] = pl;
      __syncthreads();
      buf ^= 1;
    }
  }
#pragma unroll
  for (int off = 16; off < 64; off <<= 1) {
    float mo = __shfl_xor(mr, off, 64);
    float lo = __shfl_xor(l1, off, 64);
    float nm = fmaxf(mr, mo);
    l1 = l1 * __expf(mr - nm) + lo * __expf(mo - nm);
    mr = nm;
  }
  const float inv1 = 1.f / l1;

  f32x4 oacc[4]; oacc[0] = zero; oacc[1] = zero; oacc[2] = zero; oacc[3] = zero;
  float l2 = 0.f;

  // ====== pass 2: active chunks only, barrier-free, global K/V reads ======
  for (int ch = 0; ch < 64; ++ch) {
    const float cmq = cms[wave][ch][c];
    if (!__any(cmq > mr - 18.f)) continue;   // whole chunk: t-1 == 0 exactly
    const size_t kbase = (size_t)ch * 32;
    // V fragments first (independent of scores -> overlaps K-load latency)
    bf16x8 va[4];
#pragma unroll
    for (int dt = 0; dt < 4; ++dt)
      va[dt] = *(const bf16x8*)&vt_p[(size_t)(dt * 16 + c) * SEQ + kbase + quad * 8];
#pragma unroll
    for (int kt = 0; kt < 2; ++kt) {
      const size_t rb = (kbase + kt * 16 + c) * HD;
      bf16x8 khlo = *(const bf16x8*)&kh_p[rb + quad * 8];
      bf16x8 khhi = *(const bf16x8*)&kh_p[rb + 32 + quad * 8];
      bf16x8 kllo = *(const bf16x8*)&kl_p[rb + quad * 8];
      bf16x8 klhi = *(const bf16x8*)&kl_p[rb + 32 + quad * 8];
      f32x4 sc = zero;   // identical op order to pass 1 -> bitwise-equal scores
      sc = MFMA(khlo, qf[0],  sc);
      sc = MFMA(khlo, qlf[0], sc);
      sc = MFMA(kllo, qf[0],  sc);
      sc = MFMA(khhi, qf[1],  sc);
      sc = MFMA(khhi, qlf[1], sc);
      sc = MFMA(klhi, qf[1],  sc);
      float cm = fmaxf(fmaxf(sc[0], sc[1]), fmaxf(sc[2], sc[3]));
      bf16x4 t4;
      if (cm > mr - 18.f) {
        float ls = 0.f;
#pragma unroll
        for (int r = 0; r < 4; ++r) {
          float a1 = __expf(sc[r] - mr) * inv1;  // attn1 in [0,1]
          float tv = __expf(a1) - 1.0f;          // t-1 in [0, e-1]
          ls += tv;
          t4[r] = (bf16)tv;
        }
        l2 += ls;
      } else {
        // a1 < e^-18 < 2^-24: fl(exp(a1)) == 1.0f exactly -> t-1 == 0
        t4[0] = t4[1] = t4[2] = t4[3] = (bf16)0.0f;
      }
      *(bf16x4*)&tls[wave][c][kt * 16 + quad * 4] = t4;
    }
    bf16x8 tb = *(bf16x8*)&tls[wave][c][quad * 8];
#pragma unroll
    for (int dt = 0; dt < 4; ++dt)
      oacc[dt] = MFMA(va[dt], tb, oacc[dt]);
  }

#pragma unroll
  for (int off = 16; off < 64; off <<= 1) l2 += __shfl_xor(l2, off, 64);

  const int b = bh >> 3, h = bh & 7;
  const float rcp = 1.f / (2048.f + l2);
  const float* vsp = Vs + bh * HD;
  bf16* orow = &((bf16*)O)[((size_t)b * SEQ + q0 + c) * EMB + h * HD];
#pragma unroll
  for (int dt = 0; dt < 4; ++dt) {
    f32x4 vt4 = *(const f32x4*)&vsp[dt * 16 + quad * 4];
    bf16x4 ov;
#pragma unroll
    for (int r = 0; r < 4; ++r) ov[r] = (bf16)((oacc[dt][r] + vt4[r]) * rcp);
    *(bf16x4*)&orow[dt * 16 + quad * 4] = ov;
  }
}

// ---------------------------------------------------------------------------
extern "C" void kernel_launch(void* const* d_in, const int* in_sizes, int n_in,
                              void* d_out, int out_size, void* d_ws, size_t ws_size,
                              hipStream_t stream) {
  const float* x    = (const float*)d_in[0];
  const float* Wqkv = (const float*)d_in[1];
  const float* bqkv = (const float*)d_in[2];
  const float* Wout = (const float*)d_in[3];
  const float* bout = (const float*)d_in[4];
  float* out = (float*)d_out;

  char* ws = (char*)d_ws;
  const size_t SZ = (size_t)32 * SEQ * HD * 2;  // 8 MB per array
  bf16* Qh = (bf16*)(ws + 0 * SZ);
  bf16* Ql = (bf16*)(ws + 1 * SZ);
  bf16* Kh = (bf16*)(ws + 2 * SZ);
  bf16* Kl = (bf16*)(ws + 3 * SZ);
  bf16* Vt = (bf16*)(ws + 4 * SZ);
  bf16* O  = (bf16*)(ws + 5 * SZ);
  float* Vsum = (float*)(ws + 6 * SZ);          // +8KB: per-head V column sums

  gemm_qkv<<<dim3(128, 24), 256, 0, stream>>>(x, Wqkv, bqkv, Qh, Ql, Kh, Kl, Vt);
  vsum_kernel<<<dim3(512), 256, 0, stream>>>(Vt, Vsum);
  attn_kernel<<<dim3(32, SEQ / 64), 256, 0, stream>>>(Qh, Ql, Kh, Kl, Vt, Vsum, O);
  gemm_out<<<dim3(128, 8), 256, 0, stream>>>(O, Wout, bout, out);
}

// Round 2
// 272.609 us; speedup vs baseline: 1.1438x; 1.1438x over previous
//
#include <hip/hip_runtime.h>

typedef __bf16 bf16;
typedef __attribute__((ext_vector_type(4))) __bf16 bf16x4;
typedef __attribute__((ext_vector_type(8))) __bf16 bf16x8;
typedef __attribute__((ext_vector_type(4))) float f32x4;

#define MFMA(A,B,C) __builtin_amdgcn_mfma_f32_16x16x32_bf16(A,B,C,0,0,0)

#define SEQ 2048
#define EMB 512
#define HD  64
#define SCALE 22.627416997969522f  // sqrt(512): scores are divided by E^-0.5
// Online-softmax seed: not -inf (fast-math folds inf constants to poison).
#define NEG_SEED -3.0e4f

// ---------------------------------------------------------------------------
// QKV projection: fp32 in, hi/lo split MFMA. XCD-stripe swizzle: each XCD
// (linear%8) owns a contiguous 1024-row m-stripe; within an XCD the m-block
// varies fastest -> per-XCD L2 working set = A-slice 2.1MB + W 3MB (resident).
// ---------------------------------------------------------------------------
__global__ __launch_bounds__(256)
void gemm_qkv(const float* __restrict__ A, const float* __restrict__ Bm,
              const float* __restrict__ bias,
              bf16* __restrict__ Qh, bf16* __restrict__ Ql,
              bf16* __restrict__ Kh, bf16* __restrict__ Kl,
              bf16* __restrict__ Vt) {
  __shared__ __align__(16) bf16 Ah[64][72], Al[64][72];
  __shared__ __align__(16) bf16 Bh[64][72], Bl[64][72];
  const int tid  = threadIdx.x;
  const int lane = tid & 63, wave = tid >> 6;
  // XCD-stripe swizzle (3072 blocks = 8 stripes x 16 m-blocks x 24 n-tiles)
  const int lin = blockIdx.x + gridDim.x * blockIdx.y;
  const int xcd = lin & 7;
  const int w_  = lin >> 3;                  // 0..383
  const int m0 = ((w_ & 15) + xcd * 16) * 64;
  const int n0 = (w_ >> 4) * 64;
  const int wm = (wave >> 1) * 32, wn = (wave & 1) * 32;
  const int c = lane & 15, quad = lane >> 4;
  const int fr = tid >> 4, fc = (tid & 15) * 4;

  const f32x4 zero = {0.f, 0.f, 0.f, 0.f};
  f32x4 acc[2][2];
  acc[0][0] = zero; acc[0][1] = zero; acc[1][0] = zero; acc[1][1] = zero;

  for (int k0 = 0; k0 < 512; k0 += 64) {
#pragma unroll
    for (int rr = 0; rr < 4; ++rr) {
      const int row = rr * 16 + fr;
      f32x4 av = *(const f32x4*)&A [(size_t)(m0 + row) * 512 + k0 + fc];
      f32x4 bv = *(const f32x4*)&Bm[(size_t)(n0 + row) * 512 + k0 + fc];
      bf16x4 ah, al, bh, bl;
#pragma unroll
      for (int j = 0; j < 4; ++j) {
        bf16 h = (bf16)av[j]; ah[j] = h; al[j] = (bf16)(av[j] - (float)h);
        bf16 g = (bf16)bv[j]; bh[j] = g; bl[j] = (bf16)(bv[j] - (float)g);
      }
      *(bf16x4*)&Ah[row][fc] = ah; *(bf16x4*)&Al[row][fc] = al;
      *(bf16x4*)&Bh[row][fc] = bh; *(bf16x4*)&Bl[row][fc] = bl;
    }
    __syncthreads();
#pragma unroll
    for (int ks = 0; ks < 64; ks += 32) {
      bf16x8 ah0 = *(bf16x8*)&Ah[wm + c     ][ks + quad * 8];
      bf16x8 ah1 = *(bf16x8*)&Ah[wm + 16 + c][ks + quad * 8];
      bf16x8 al0 = *(bf16x8*)&Al[wm + c     ][ks + quad * 8];
      bf16x8 al1 = *(bf16x8*)&Al[wm + 16 + c][ks + quad * 8];
      bf16x8 bh0 = *(bf16x8*)&Bh[wn + c     ][ks + quad * 8];
      bf16x8 bh1 = *(bf16x8*)&Bh[wn + 16 + c][ks + quad * 8];
      bf16x8 bl0 = *(bf16x8*)&Bl[wn + c     ][ks + quad * 8];
      bf16x8 bl1 = *(bf16x8*)&Bl[wn + 16 + c][ks + quad * 8];
      acc[0][0] = MFMA(ah0, bh0, acc[0][0]);
      acc[0][0] = MFMA(al0, bh0, acc[0][0]);
      acc[0][0] = MFMA(ah0, bl0, acc[0][0]);
      acc[0][1] = MFMA(ah0, bh1, acc[0][1]);
      acc[0][1] = MFMA(al0, bh1, acc[0][1]);
      acc[0][1] = MFMA(ah0, bl1, acc[0][1]);
      acc[1][0] = MFMA(ah1, bh0, acc[1][0]);
      acc[1][0] = MFMA(al1, bh0, acc[1][0]);
      acc[1][0] = MFMA(ah1, bl0, acc[1][0]);
      acc[1][1] = MFMA(ah1, bh1, acc[1][1]);
      acc[1][1] = MFMA(al1, bh1, acc[1][1]);
      acc[1][1] = MFMA(ah1, bl1, acc[1][1]);
    }
    __syncthreads();
  }

#pragma unroll
  for (int mt = 0; mt < 2; ++mt) {
#pragma unroll
    for (int nt = 0; nt < 2; ++nt) {
      const int n = n0 + wn + nt * 16 + c;
      const float bv = bias[n];
#pragma unroll
      for (int r = 0; r < 4; ++r) {
        const int m = m0 + wm + mt * 16 + quad * 4 + r;
        float v = acc[mt][nt][r] + bv;
        const int h = n / 192, t = n % 192;
        const size_t bh = (size_t)((m >> 11) * 8 + h);
        const int s = m & 2047;
        if (t < 64) {
          float q = v * SCALE;
          bf16 hi = (bf16)q;
          float lo = q - (float)hi;
          size_t idx = (bh * SEQ + s) * HD + t;
          Qh[idx] = hi; Ql[idx] = (bf16)lo;
        } else if (t < 128) {
          bf16 hi = (bf16)v;
          float lo = v - (float)hi;
          size_t idx = (bh * SEQ + s) * HD + (t - 64);
          Kh[idx] = hi; Kl[idx] = (bf16)lo;
        } else {
          Vt[(bh * HD + (t - 128)) * SEQ + s] = (bf16)v;
        }
      }
    }
  }
}

// ---------------------------------------------------------------------------
// Output projection: fp32 out. Same XCD-stripe swizzle (1024 blocks).
// ---------------------------------------------------------------------------
__global__ __launch_bounds__(256)
void gemm_out(const bf16* __restrict__ A, const float* __restrict__ Bm,
              const float* __restrict__ bias, float* __restrict__ C) {
  __shared__ __align__(16) bf16 As[64][72];
  __shared__ __align__(16) bf16 Bs[64][72];
  const int tid  = threadIdx.x;
  const int lane = tid & 63, wave = tid >> 6;
  const int lin = blockIdx.x + gridDim.x * blockIdx.y;
  const int xcd = lin & 7;
  const int w_  = lin >> 3;                  // 0..127
  const int m0 = ((w_ & 15) + xcd * 16) * 64;
  const int n0 = (w_ >> 4) * 64;
  const int wm = (wave >> 1) * 32, wn = (wave & 1) * 32;
  const int c = lane & 15, quad = lane >> 4;
  const int lr = tid >> 3, lc = (tid & 7) * 8;
  const int fr = tid >> 4, fc = (tid & 15) * 4;

  const f32x4 zero = {0.f, 0.f, 0.f, 0.f};
  f32x4 acc[2][2];
  acc[0][0] = zero; acc[0][1] = zero; acc[1][0] = zero; acc[1][1] = zero;

  for (int k0 = 0; k0 < 512; k0 += 64) {
    *(bf16x8*)&As[lr][lc]      = *(const bf16x8*)&A[(size_t)(m0 + lr     ) * 512 + k0 + lc];
    *(bf16x8*)&As[lr + 32][lc] = *(const bf16x8*)&A[(size_t)(m0 + lr + 32) * 512 + k0 + lc];
#pragma unroll
    for (int rr = 0; rr < 4; ++rr) {
      const int row = rr * 16 + fr;
      f32x4 bv = *(const f32x4*)&Bm[(size_t)(n0 + row) * 512 + k0 + fc];
      bf16x4 bb;
#pragma unroll
      for (int j = 0; j < 4; ++j) bb[j] = (bf16)bv[j];
      *(bf16x4*)&Bs[row][fc] = bb;
    }
    __syncthreads();
#pragma unroll
    for (int ks = 0; ks < 64; ks += 32) {
      bf16x8 a0 = *(bf16x8*)&As[wm + c     ][ks + quad * 8];
      bf16x8 a1 = *(bf16x8*)&As[wm + 16 + c][ks + quad * 8];
      bf16x8 b0 = *(bf16x8*)&Bs[wn + c     ][ks + quad * 8];
      bf16x8 b1 = *(bf16x8*)&Bs[wn + 16 + c][ks + quad * 8];
      acc[0][0] = MFMA(a0, b0, acc[0][0]);
      acc[0][1] = MFMA(a0, b1, acc[0][1]);
      acc[1][0] = MFMA(a1, b0, acc[1][0]);
      acc[1][1] = MFMA(a1, b1, acc[1][1]);
    }
    __syncthreads();
  }

#pragma unroll
  for (int mt = 0; mt < 2; ++mt) {
#pragma unroll
    for (int nt = 0; nt < 2; ++nt) {
      const int n = n0 + wn + nt * 16 + c;
      const float bv = bias[n];
#pragma unroll
      for (int r = 0; r < 4; ++r) {
        const int m = m0 + wm + mt * 16 + quad * 4 + r;
        C[(size_t)m * 512 + n] = acc[mt][nt][r] + bv;
      }
    }
  }
}

// ---------------------------------------------------------------------------
// Per-head V column sums: Vtot[bh][d] = sum_s Vt[bh][d][s].
// One wave per (bh,d) row; 8MB read, L2/L3-resident, ~3us.
// ---------------------------------------------------------------------------
__global__ __launch_bounds__(256)
void vsum_kernel(const bf16* __restrict__ Vt, float* __restrict__ Vs) {
  const int row  = blockIdx.x * 4 + (threadIdx.x >> 6);   // 0..2047
  const int lane = threadIdx.x & 63;
  const bf16* p = Vt + (size_t)row * SEQ;
  float s = 0.f;
#pragma unroll
  for (int it = 0; it < 4; ++it) {
    bf16x8 v = *(const bf16x8*)&p[(it * 64 + lane) * 8];
#pragma unroll
    for (int j = 0; j < 8; ++j) s += (float)v[j];
  }
#pragma unroll
  for (int off = 1; off < 64; off <<= 1) s += __shfl_xor(s, off, 64);
  if (lane == 0) Vs[row] = s;
}

// ---------------------------------------------------------------------------
// Attention, double softmax. Round-0 lockstep skeleton (dbuf LDS staging +
// barriers, proven 148us) + round-1 math (proven exact):
//   O = Vtot + sum_k (t_k - 1) V_k,  l2 = 2048 + sum (t_k - 1),  t = exp(attn1)
// Pass 1 records per-query chunk maxes (bf16) in LDS. Pass 2 stages K/V for
// ALL chunks (block-uniform, pipelined) but gates the expensive body (8 LDS
// K-reads, 12 QK MFMAs, exp, tls, 4 PV MFMAs) per WAVE on cms > mr-22 --
// a strict superset of the per-lane mr-18 test (bf16 err <= 4), so skipped
// chunks would have produced exactly t-1 = 0: zero added error. ~20/64
// chunks are wave-active -> ~70% of pass-2 compute gone, pipeline intact.
// ---------------------------------------------------------------------------
__global__ __launch_bounds__(256, 4)
void attn_kernel(const bf16* __restrict__ Qh, const bf16* __restrict__ Ql,
                 const bf16* __restrict__ Kh, const bf16* __restrict__ Kl,
                 const bf16* __restrict__ Vt, const float* __restrict__ Vs,
                 bf16* __restrict__ O) {
  __shared__ __align__(16) bf16 KhS[2][32][64];  // [key][d], chunk^=(row&7)
  __shared__ __align__(16) bf16 KlS[2][32][64];
  __shared__ __align__(16) bf16 VtS[2][64][32];  // [d][key], chunk^=(row&3)
  __shared__ __align__(16) bf16 tls[4][16][40];  // per-wave t^T[q][key], +8 pad
  __shared__ bf16 cmsB[4][64][16];               // per-wave per-chunk per-query max
  const int tid  = threadIdx.x;
  const int lane = tid & 63, wave = tid >> 6;
  const int c = lane & 15, quad = lane >> 4;
  const int bh = blockIdx.x;
  const int q0 = blockIdx.y * 64 + wave * 16;
  const size_t hoff = (size_t)bh * SEQ * HD;
  const bf16* qh_p = Qh + hoff;
  const bf16* ql_p = Ql + hoff;
  const bf16* kh_p = Kh + hoff;
  const bf16* kl_p = Kl + hoff;
  const bf16* vt_p = Vt + hoff;                  // [HD][SEQ]
  const f32x4 zero = {0.f, 0.f, 0.f, 0.f};

  const int krow = tid >> 3;
  const int kcol = (tid & 7) * 8;
  const int kphy = ((tid & 7) ^ (krow & 7)) * 8;
  const int vrow = tid >> 2;
  const int vcol = (tid & 3) * 8;
  const int vphy = ((tid & 3) ^ (vrow & 3)) * 8;
  const int pc0 = ((0 + quad) ^ (c & 7)) * 8;
  const int pc1 = ((4 + quad) ^ (c & 7)) * 8;
  const int vpc = (quad ^ (c & 3)) * 8;

  bf16x8 qf[2], qlf[2];
#pragma unroll
  for (int t = 0; t < 2; ++t) {
    size_t off = (size_t)(q0 + c) * HD + t * 32 + quad * 8;
    qf[t]  = *(const bf16x8*)&qh_p[off];
    qlf[t] = *(const bf16x8*)&ql_p[off];
  }

  float mr = NEG_SEED, l1 = 0.f;

  // ================= pass 1: online (m, L1), sparse; record chunk maxes ====
  bf16x8 ph, pl, pv;
  ph = *(const bf16x8*)&kh_p[(size_t)krow * HD + kcol];
  pl = *(const bf16x8*)&kl_p[(size_t)krow * HD + kcol];
  *(bf16x8*)&KhS[0][krow][kphy] = ph;
  *(bf16x8*)&KlS[0][krow][kphy] = pl;
  __syncthreads();
  int buf = 0;
  for (int ch = 0; ch < 64; ++ch) {
    if (ch < 63) {
      const size_t k0 = (size_t)(ch + 1) * 32;
      ph = *(const bf16x8*)&kh_p[(k0 + krow) * HD + kcol];
      pl = *(const bf16x8*)&kl_p[(k0 + krow) * HD + kcol];
    }
    float cmc = -3.4e38f;
#pragma unroll
    for (int kt = 0; kt < 2; ++kt) {
      const int row = kt * 16 + c;
      bf16x8 kh0 = *(bf16x8*)&KhS[buf][row][pc0];
      bf16x8 kl0 = *(bf16x8*)&KlS[buf][row][pc0];
      bf16x8 kh1 = *(bf16x8*)&KhS[buf][row][pc1];
      bf16x8 kl1 = *(bf16x8*)&KlS[buf][row][pc1];
      f32x4 sc = zero;
      sc = MFMA(kh0, qf[0],  sc);
      sc = MFMA(kh0, qlf[0], sc);
      sc = MFMA(kl0, qf[0],  sc);
      sc = MFMA(kh1, qf[1],  sc);
      sc = MFMA(kh1, qlf[1], sc);
      sc = MFMA(kl1, qf[1],  sc);
      float cm = fmaxf(fmaxf(sc[0], sc[1]), fmaxf(sc[2], sc[3]));
      cmc = fmaxf(cmc, cm);
      if (cm > mr - 90.f) {   // else: all exp(s-m) underflow to 0 exactly
        float nm = fmaxf(mr, cm);
        l1 = l1 * __expf(mr - nm) + __expf(sc[0] - nm) + __expf(sc[1] - nm)
                                  + __expf(sc[2] - nm) + __expf(sc[3] - nm);
        mr = nm;
      }
    }
    // per-query chunk max (reduce across the 4 quad lanes of query c)
    cmc = fmaxf(cmc, __shfl_xor(cmc, 16, 64));
    cmc = fmaxf(cmc, __shfl_xor(cmc, 32, 64));
    if (quad == 0) cmsB[wave][ch][c] = (bf16)cmc;
    if (ch < 63) {
      *(bf16x8*)&KhS[buf ^ 1][krow][kphy] = ph;
      *(bf16x8*)&KlS[buf ^ 1][krow][kphy] = pl;
      __syncthreads();
      buf ^= 1;
    }
  }
#pragma unroll
  for (int off = 16; off < 64; off <<= 1) {
    float mo = __shfl_xor(mr, off, 64);
    float lo = __shfl_xor(l1, off, 64);
    float nm = fmaxf(mr, mo);
    l1 = l1 * __expf(mr - nm) + lo * __expf(mo - nm);
    mr = nm;
  }
  const float inv1 = 1.f / l1;

  f32x4 oacc[4]; oacc[0] = zero; oacc[1] = zero; oacc[2] = zero; oacc[3] = zero;
  float l2 = 0.f;

  // ====== pass 2: lockstep staging for all chunks, wave-gated compute ======
  ph = *(const bf16x8*)&kh_p[(size_t)krow * HD + kcol];
  pl = *(const bf16x8*)&kl_p[(size_t)krow * HD + kcol];
  pv = *(const bf16x8*)&vt_p[(size_t)vrow * SEQ + vcol];
  *(bf16x8*)&KhS[0][krow][kphy] = ph;
  *(bf16x8*)&KlS[0][krow][kphy] = pl;
  *(bf16x8*)&VtS[0][vrow][vphy] = pv;
  __syncthreads();
  buf = 0;
  for (int ch = 0; ch < 64; ++ch) {
    if (ch < 63) {
      const size_t k0 = (size_t)(ch + 1) * 32;
      ph = *(const bf16x8*)&kh_p[(k0 + krow) * HD + kcol];
      pl = *(const bf16x8*)&kl_p[(k0 + krow) * HD + kcol];
      pv = *(const bf16x8*)&vt_p[(size_t)vrow * SEQ + k0 + vcol];
    }
    if (__any((float)cmsB[wave][ch][c] > mr - 22.f)) {
#pragma unroll
      for (int kt = 0; kt < 2; ++kt) {
        const int row = kt * 16 + c;
        bf16x8 kh0 = *(bf16x8*)&KhS[buf][row][pc0];
        bf16x8 kl0 = *(bf16x8*)&KlS[buf][row][pc0];
        bf16x8 kh1 = *(bf16x8*)&KhS[buf][row][pc1];
        bf16x8 kl1 = *(bf16x8*)&KlS[buf][row][pc1];
        f32x4 sc = zero;   // identical op order to pass 1 -> bitwise-equal
        sc = MFMA(kh0, qf[0],  sc);
        sc = MFMA(kh0, qlf[0], sc);
        sc = MFMA(kl0, qf[0],  sc);
        sc = MFMA(kh1, qf[1],  sc);
        sc = MFMA(kh1, qlf[1], sc);
        sc = MFMA(kl1, qf[1],  sc);
        float cm = fmaxf(fmaxf(sc[0], sc[1]), fmaxf(sc[2], sc[3]));
        bf16x4 t4;
        if (cm > mr - 18.f) {
          float ls = 0.f;
#pragma unroll
          for (int r = 0; r < 4; ++r) {
            float a1 = __expf(sc[r] - mr) * inv1;  // attn1 in [0,1]
            float tv = __expf(a1) - 1.0f;          // t-1 in [0, e-1]
            ls += tv;
            t4[r] = (bf16)tv;
          }
          l2 += ls;
        } else {
          // a1 < e^-18 < 2^-24: fl(exp(a1)) == 1.0f exactly -> t-1 == 0
          t4[0] = t4[1] = t4[2] = t4[3] = (bf16)0.0f;
        }
        *(bf16x4*)&tls[wave][c][kt * 16 + quad * 4] = t4;
      }
      bf16x8 tb = *(bf16x8*)&tls[wave][c][quad * 8];
#pragma unroll
      for (int dt = 0; dt < 4; ++dt) {
        bf16x8 va = *(bf16x8*)&VtS[buf][dt * 16 + c][vpc];
        oacc[dt] = MFMA(va, tb, oacc[dt]);
      }
    }
    if (ch < 63) {
      *(bf16x8*)&KhS[buf ^ 1][krow][kphy] = ph;
      *(bf16x8*)&KlS[buf ^ 1][krow][kphy] = pl;
      *(bf16x8*)&VtS[buf ^ 1][vrow][vphy] = pv;
      __syncthreads();
      buf ^= 1;
    }
  }

#pragma unroll
  for (int off = 16; off < 64; off <<= 1) l2 += __shfl_xor(l2, off, 64);

  const int b = bh >> 3, h = bh & 7;
  const float rcp = 1.f / (2048.f + l2);
  const float* vsp = Vs + bh * HD;
  bf16* orow = &((bf16*)O)[((size_t)b * SEQ + q0 + c) * EMB + h * HD];
#pragma unroll
  for (int dt = 0; dt < 4; ++dt) {
    f32x4 vt4 = *(const f32x4*)&vsp[dt * 16 + quad * 4];
    bf16x4 ov;
#pragma unroll
    for (int r = 0; r < 4; ++r) ov[r] = (bf16)((oacc[dt][r] + vt4[r]) * rcp);
    *(bf16x4*)&orow[dt * 16 + quad * 4] = ov;
  }
}

// ---------------------------------------------------------------------------
extern "C" void kernel_launch(void* const* d_in, const int* in_sizes, int n_in,
                              void* d_out, int out_size, void* d_ws, size_t ws_size,
                              hipStream_t stream) {
  const float* x    = (const float*)d_in[0];
  const float* Wqkv = (const float*)d_in[1];
  const float* bqkv = (const float*)d_in[2];
  const float* Wout = (const float*)d_in[3];
  const float* bout = (const float*)d_in[4];
  float* out = (float*)d_out;

  char* ws = (char*)d_ws;
  const size_t SZ = (size_t)32 * SEQ * HD * 2;  // 8 MB per array
  bf16* Qh = (bf16*)(ws + 0 * SZ);
  bf16* Ql = (bf16*)(ws + 1 * SZ);
  bf16* Kh = (bf16*)(ws + 2 * SZ);
  bf16* Kl = (bf16*)(ws + 3 * SZ);
  bf16* Vt = (bf16*)(ws + 4 * SZ);
  bf16* O  = (bf16*)(ws + 5 * SZ);
  float* Vsum = (float*)(ws + 6 * SZ);          // +8KB: per-head V column sums

  gemm_qkv<<<dim3(128, 24), 256, 0, stream>>>(x, Wqkv, bqkv, Qh, Ql, Kh, Kl, Vt);
  vsum_kernel<<<dim3(512), 256, 0, stream>>>(Vt, Vsum);
  attn_kernel<<<dim3(32, SEQ / 64), 256, 0, stream>>>(Qh, Ql, Kh, Kl, Vt, Vsum, O);
  gemm_out<<<dim3(128, 8), 256, 0, stream>>>(O, Wout, bout, out);
}

// Round 3
// 244.106 us; speedup vs baseline: 1.2773x; 1.1168x over previous
//
#include <hip/hip_runtime.h>

typedef __bf16 bf16;
typedef __attribute__((ext_vector_type(4))) __bf16 bf16x4;
typedef __attribute__((ext_vector_type(8))) __bf16 bf16x8;
typedef __attribute__((ext_vector_type(4))) float f32x4;

#define MFMA(A,B,C) __builtin_amdgcn_mfma_f32_16x16x32_bf16(A,B,C,0,0,0)

#define SEQ 2048
#define EMB 512
#define HD  64
#define SCALE 22.627416997969522f  // sqrt(512): scores are divided by E^-0.5
// Online-softmax seed: not -inf (fast-math folds inf constants to poison).
#define NEG_SEED -3.0e4f

// ---------------------------------------------------------------------------
// QKV projection: fp32 in, hi/lo split MFMA. XCD-stripe swizzle. V is written
// ROW-major (Vrm[s][d]) now: attention's finish phase gathers whole V rows.
// ---------------------------------------------------------------------------
__global__ __launch_bounds__(256)
void gemm_qkv(const float* __restrict__ A, const float* __restrict__ Bm,
              const float* __restrict__ bias,
              bf16* __restrict__ Qh, bf16* __restrict__ Ql,
              bf16* __restrict__ Kh, bf16* __restrict__ Kl,
              bf16* __restrict__ Vrm) {
  __shared__ __align__(16) bf16 Ah[64][72], Al[64][72];
  __shared__ __align__(16) bf16 Bh[64][72], Bl[64][72];
  const int tid  = threadIdx.x;
  const int lane = tid & 63, wave = tid >> 6;
  const int lin = blockIdx.x + gridDim.x * blockIdx.y;
  const int xcd = lin & 7;
  const int w_  = lin >> 3;                  // 0..383
  const int m0 = ((w_ & 15) + xcd * 16) * 64;
  const int n0 = (w_ >> 4) * 64;
  const int wm = (wave >> 1) * 32, wn = (wave & 1) * 32;
  const int c = lane & 15, quad = lane >> 4;
  const int fr = tid >> 4, fc = (tid & 15) * 4;

  const f32x4 zero = {0.f, 0.f, 0.f, 0.f};
  f32x4 acc[2][2];
  acc[0][0] = zero; acc[0][1] = zero; acc[1][0] = zero; acc[1][1] = zero;

  for (int k0 = 0; k0 < 512; k0 += 64) {
#pragma unroll
    for (int rr = 0; rr < 4; ++rr) {
      const int row = rr * 16 + fr;
      f32x4 av = *(const f32x4*)&A [(size_t)(m0 + row) * 512 + k0 + fc];
      f32x4 bv = *(const f32x4*)&Bm[(size_t)(n0 + row) * 512 + k0 + fc];
      bf16x4 ah, al, bh, bl;
#pragma unroll
      for (int j = 0; j < 4; ++j) {
        bf16 h = (bf16)av[j]; ah[j] = h; al[j] = (bf16)(av[j] - (float)h);
        bf16 g = (bf16)bv[j]; bh[j] = g; bl[j] = (bf16)(bv[j] - (float)g);
      }
      *(bf16x4*)&Ah[row][fc] = ah; *(bf16x4*)&Al[row][fc] = al;
      *(bf16x4*)&Bh[row][fc] = bh; *(bf16x4*)&Bl[row][fc] = bl;
    }
    __syncthreads();
#pragma unroll
    for (int ks = 0; ks < 64; ks += 32) {
      bf16x8 ah0 = *(bf16x8*)&Ah[wm + c     ][ks + quad * 8];
      bf16x8 ah1 = *(bf16x8*)&Ah[wm + 16 + c][ks + quad * 8];
      bf16x8 al0 = *(bf16x8*)&Al[wm + c     ][ks + quad * 8];
      bf16x8 al1 = *(bf16x8*)&Al[wm + 16 + c][ks + quad * 8];
      bf16x8 bh0 = *(bf16x8*)&Bh[wn + c     ][ks + quad * 8];
      bf16x8 bh1 = *(bf16x8*)&Bh[wn + 16 + c][ks + quad * 8];
      bf16x8 bl0 = *(bf16x8*)&Bl[wn + c     ][ks + quad * 8];
      bf16x8 bl1 = *(bf16x8*)&Bl[wn + 16 + c][ks + quad * 8];
      acc[0][0] = MFMA(ah0, bh0, acc[0][0]);
      acc[0][0] = MFMA(al0, bh0, acc[0][0]);
      acc[0][0] = MFMA(ah0, bl0, acc[0][0]);
      acc[0][1] = MFMA(ah0, bh1, acc[0][1]);
      acc[0][1] = MFMA(al0, bh1, acc[0][1]);
      acc[0][1] = MFMA(ah0, bl1, acc[0][1]);
      acc[1][0] = MFMA(ah1, bh0, acc[1][0]);
      acc[1][0] = MFMA(al1, bh0, acc[1][0]);
      acc[1][0] = MFMA(ah1, bl0, acc[1][0]);
      acc[1][1] = MFMA(ah1, bh1, acc[1][1]);
      acc[1][1] = MFMA(al1, bh1, acc[1][1]);
      acc[1][1] = MFMA(ah1, bl1, acc[1][1]);
    }
    __syncthreads();
  }

#pragma unroll
  for (int mt = 0; mt < 2; ++mt) {
#pragma unroll
    for (int nt = 0; nt < 2; ++nt) {
      const int n = n0 + wn + nt * 16 + c;
      const float bv = bias[n];
#pragma unroll
      for (int r = 0; r < 4; ++r) {
        const int m = m0 + wm + mt * 16 + quad * 4 + r;
        float v = acc[mt][nt][r] + bv;
        const int h = n / 192, t = n % 192;
        const size_t bh = (size_t)((m >> 11) * 8 + h);
        const int s = m & 2047;
        if (t < 64) {
          float q = v * SCALE;
          bf16 hi = (bf16)q;
          float lo = q - (float)hi;
          size_t idx = (bh * SEQ + s) * HD + t;
          Qh[idx] = hi; Ql[idx] = (bf16)lo;
        } else if (t < 128) {
          bf16 hi = (bf16)v;
          float lo = v - (float)hi;
          size_t idx = (bh * SEQ + s) * HD + (t - 64);
          Kh[idx] = hi; Kl[idx] = (bf16)lo;
        } else {
          Vrm[(bh * SEQ + s) * HD + (t - 128)] = (bf16)v;
        }
      }
    }
  }
}

// ---------------------------------------------------------------------------
// Output projection: fp32 out. Same XCD-stripe swizzle (1024 blocks).
// ---------------------------------------------------------------------------
__global__ __launch_bounds__(256)
void gemm_out(const bf16* __restrict__ A, const float* __restrict__ Bm,
              const float* __restrict__ bias, float* __restrict__ C) {
  __shared__ __align__(16) bf16 As[64][72];
  __shared__ __align__(16) bf16 Bs[64][72];
  const int tid  = threadIdx.x;
  const int lane = tid & 63, wave = tid >> 6;
  const int lin = blockIdx.x + gridDim.x * blockIdx.y;
  const int xcd = lin & 7;
  const int w_  = lin >> 3;                  // 0..127
  const int m0 = ((w_ & 15) + xcd * 16) * 64;
  const int n0 = (w_ >> 4) * 64;
  const int wm = (wave >> 1) * 32, wn = (wave & 1) * 32;
  const int c = lane & 15, quad = lane >> 4;
  const int lr = tid >> 3, lc = (tid & 7) * 8;
  const int fr = tid >> 4, fc = (tid & 15) * 4;

  const f32x4 zero = {0.f, 0.f, 0.f, 0.f};
  f32x4 acc[2][2];
  acc[0][0] = zero; acc[0][1] = zero; acc[1][0] = zero; acc[1][1] = zero;

  for (int k0 = 0; k0 < 512; k0 += 64) {
    *(bf16x8*)&As[lr][lc]      = *(const bf16x8*)&A[(size_t)(m0 + lr     ) * 512 + k0 + lc];
    *(bf16x8*)&As[lr + 32][lc] = *(const bf16x8*)&A[(size_t)(m0 + lr + 32) * 512 + k0 + lc];
#pragma unroll
    for (int rr = 0; rr < 4; ++rr) {
      const int row = rr * 16 + fr;
      f32x4 bv = *(const f32x4*)&Bm[(size_t)(n0 + row) * 512 + k0 + fc];
      bf16x4 bb;
#pragma unroll
      for (int j = 0; j < 4; ++j) bb[j] = (bf16)bv[j];
      *(bf16x4*)&Bs[row][fc] = bb;
    }
    __syncthreads();
#pragma unroll
    for (int ks = 0; ks < 64; ks += 32) {
      bf16x8 a0 = *(bf16x8*)&As[wm + c     ][ks + quad * 8];
      bf16x8 a1 = *(bf16x8*)&As[wm + 16 + c][ks + quad * 8];
      bf16x8 b0 = *(bf16x8*)&Bs[wn + c     ][ks + quad * 8];
      bf16x8 b1 = *(bf16x8*)&Bs[wn + 16 + c][ks + quad * 8];
      acc[0][0] = MFMA(a0, b0, acc[0][0]);
      acc[0][1] = MFMA(a0, b1, acc[0][1]);
      acc[1][0] = MFMA(a1, b0, acc[1][0]);
      acc[1][1] = MFMA(a1, b1, acc[1][1]);
    }
    __syncthreads();
  }

#pragma unroll
  for (int mt = 0; mt < 2; ++mt) {
#pragma unroll
    for (int nt = 0; nt < 2; ++nt) {
      const int n = n0 + wn + nt * 16 + c;
      const float bv = bias[n];
#pragma unroll
      for (int r = 0; r < 4; ++r) {
        const int m = m0 + wm + mt * 16 + quad * 4 + r;
        C[(size_t)m * 512 + n] = acc[mt][nt][r] + bv;
      }
    }
  }
}

// ---------------------------------------------------------------------------
// Per-head V column sums from row-major V: Vs[bh][d] = sum_s Vrm[bh][s][d].
// One block per head; coalesced bf16x8 reads; ~2-3us.
// ---------------------------------------------------------------------------
__global__ __launch_bounds__(256)
void vsum_kernel(const bf16* __restrict__ Vrm, float* __restrict__ Vs) {
  __shared__ float red[32][64];
  const int bh = blockIdx.x;
  const bf16* p = Vrm + (size_t)bh * SEQ * HD;
  const int g  = threadIdx.x >> 3;        // 0..31 row group
  const int dc = (threadIdx.x & 7) * 8;   // dim chunk
  float s[8] = {0.f,0.f,0.f,0.f,0.f,0.f,0.f,0.f};
  for (int s0 = g; s0 < SEQ; s0 += 32) {
    bf16x8 v = *(const bf16x8*)&p[(size_t)s0 * HD + dc];
#pragma unroll
    for (int j = 0; j < 8; ++j) s[j] += (float)v[j];
  }
#pragma unroll
  for (int j = 0; j < 8; ++j) red[g][dc + j] = s[j];
  __syncthreads();
  if (threadIdx.x < 64) {
    float a = 0.f;
#pragma unroll
    for (int g2 = 0; g2 < 32; ++g2) a += red[g2][threadIdx.x];
    Vs[bh * HD + threadIdx.x] = a;
  }
}

// ---------------------------------------------------------------------------
// Attention, double softmax, shift-invariant 3-phase form.
//   O = [Vtot + sum_k (t_k-1) V_k] / l2,  t = exp(exp(s-m~)/l1),
//   l1 = sum exp(s-m~) -- EXACT for ANY shift m~ (softmax shift-invariance),
//   so no true max and no online-rescale chain are needed.
// Phase SCAN: s~ = Kh.Qh (1 MFMA/tile, |s~-s| <~ 3): per-query shift m~ and
//   per-16-key-tile maxes (u8, LDS). All 2048 keys, Kh-only staging.
// Phase B: exact 6-MFMA scores ONLY for tiles with cms~ > m~-28 (~20%).
//   Gate-missed tiles have s < m~-20: l1 tail < 3e-4 rel, t-1 < 1.2e-7 each
//   (suppressed by /2048 to <1e-6 in O). l1 via plain adds; keys with
//   s-m~ > -16 (~2/query) push (p=exp(s-m~), idx) to a per-query LDS list.
// Phase C: per stored key: t-1 = exp(p/l1)-1, gather V row, VALU accumulate.
//   No V staging, no PV MFMA, no t round-trip, no second K staging pass.
// 8 waves/block (128 queries) halve staging traffic; 32 staged iters total.
// ---------------------------------------------------------------------------
__global__ __launch_bounds__(512, 4)
void attn_kernel(const bf16* __restrict__ Qh, const bf16* __restrict__ Ql,
                 const bf16* __restrict__ Kh, const bf16* __restrict__ Kl,
                 const bf16* __restrict__ Vrm, const float* __restrict__ Vs,
                 bf16* __restrict__ O) {
  __shared__ __align__(16) char pool[32768];     // Kh stage [2][128][64] bf16
  __shared__ unsigned char cms8[8][128][16];     // per-wave tile-max (s~/8+128)
  __shared__ float plistP[8][16][16];            // per-query p list
  __shared__ unsigned short plistI[8][16][16];   // per-query key-idx list
  __shared__ int pcnt[8][16];
  bf16 (*SK)[64] = (bf16(*)[64])pool;

  const int tid  = threadIdx.x;
  const int lane = tid & 63, wave = tid >> 6;
  const int c = lane & 15, quad = lane >> 4;
  const int bh = blockIdx.x;
  const int q0 = blockIdx.y * 128 + wave * 16;
  const size_t hoff = (size_t)bh * SEQ * HD;
  const bf16* qh_p = Qh + hoff;
  const bf16* ql_p = Ql + hoff;
  const bf16* kh_p = Kh + hoff;
  const bf16* kl_p = Kl + hoff;
  const bf16* v_p  = Vrm + hoff;
  const f32x4 zero = {0.f, 0.f, 0.f, 0.f};

  const int sr   = tid >> 3;                     // 0..63 staging row
  const int scol = (tid & 7) * 8;
  const int sphy = ((tid & 7) ^ (sr & 7)) * 8;
  const int pc0  = ((0 + quad) ^ (c & 7)) * 8;
  const int pc1  = ((4 + quad) ^ (c & 7)) * 8;

  bf16x8 qf[2], qlf[2];
#pragma unroll
  for (int t = 0; t < 2; ++t) {
    size_t off = (size_t)(q0 + c) * HD + t * 32 + quad * 8;
    qf[t]  = *(const bf16x8*)&qh_p[off];
    qlf[t] = *(const bf16x8*)&ql_p[off];
  }

  // ====================== phase SCAN: hi-only s~ ======================
  bf16x8 pA = *(const bf16x8*)&kh_p[(size_t)sr * HD + scol];
  bf16x8 pB = *(const bf16x8*)&kh_p[(size_t)(sr + 64) * HD + scol];
  *(bf16x8*)&SK[sr][sphy]      = pA;
  *(bf16x8*)&SK[sr + 64][sphy] = pB;
  __syncthreads();
  int buf = 0;
  float mqL = NEG_SEED;
  for (int cs = 0; cs < 16; ++cs) {
    if (cs < 15) {
      const size_t k0 = (size_t)(cs + 1) * 128;
      pA = *(const bf16x8*)&kh_p[(k0 + sr) * HD + scol];
      pB = *(const bf16x8*)&kh_p[(k0 + sr + 64) * HD + scol];
    }
#pragma unroll
    for (int t = 0; t < 8; ++t) {
      bf16x8 k0 = *(bf16x8*)&SK[buf * 128 + t * 16 + c][pc0];
      bf16x8 k1 = *(bf16x8*)&SK[buf * 128 + t * 16 + c][pc1];
      f32x4 sc = MFMA(k0, qf[0], zero);
      sc = MFMA(k1, qf[1], sc);
      float cm = fmaxf(fmaxf(sc[0], sc[1]), fmaxf(sc[2], sc[3]));
      mqL = fmaxf(mqL, cm);
      float c2 = fmaxf(cm, __shfl_xor(cm, 16, 64));
      c2 = fmaxf(c2, __shfl_xor(c2, 32, 64));
      if (quad == 0) {
        int qv = (int)(c2 * 0.125f + 128.5f);
        qv = qv < 0 ? 0 : (qv > 255 ? 255 : qv);
        cms8[wave][cs * 8 + t][c] = (unsigned char)qv;
      }
    }
    if (cs < 15) {
      const int nb = buf ^ 1;
      *(bf16x8*)&SK[nb * 128 + sr][sphy]      = pA;
      *(bf16x8*)&SK[nb * 128 + sr + 64][sphy] = pB;
      __syncthreads();
      buf = nb;
    }
  }
  __syncthreads();   // all waves done reading SK before phase-B restaging
  float mq = fmaxf(mqL, __shfl_xor(mqL, 16, 64));
  mq = fmaxf(mq, __shfl_xor(mq, 32, 64));

  // ====================== phase B: exact scores, gated ======================
  if (lane < 16) pcnt[wave][lane] = 0;   // same-wave use only
  pA = *(const bf16x8*)&kh_p[(size_t)sr * HD + scol];
  pB = *(const bf16x8*)&kh_p[(size_t)(sr + 64) * HD + scol];
  *(bf16x8*)&SK[sr][sphy]      = pA;
  *(bf16x8*)&SK[sr + 64][sphy] = pB;
  __syncthreads();
  buf = 0;
  float l1 = 0.f;
  for (int cb = 0; cb < 16; ++cb) {
    if (cb < 15) {
      const size_t k0 = (size_t)(cb + 1) * 128;
      pA = *(const bf16x8*)&kh_p[(k0 + sr) * HD + scol];
      pB = *(const bf16x8*)&kh_p[(k0 + sr + 64) * HD + scol];
    }
#pragma unroll
    for (int t = 0; t < 8; ++t) {
      const int g = cb * 8 + t;
      const float cv = (float)((int)cms8[wave][g][c] - 128) * 8.0f;
      if (__any(cv > mq - 28.f)) {
        bf16x8 kh0 = *(bf16x8*)&SK[buf * 128 + t * 16 + c][pc0];
        bf16x8 kh1 = *(bf16x8*)&SK[buf * 128 + t * 16 + c][pc1];
        const size_t krow = (size_t)(g * 16 + c) * HD;
        bf16x8 kl0 = *(const bf16x8*)&kl_p[krow + quad * 8];
        bf16x8 kl1 = *(const bf16x8*)&kl_p[krow + 32 + quad * 8];
        f32x4 sc = MFMA(kh0, qf[0], zero);   // kl terms last: global-load
        sc = MFMA(kh0, qlf[0], sc);          // latency hides behind kh MFMAs
        sc = MFMA(kh1, qf[1],  sc);
        sc = MFMA(kh1, qlf[1], sc);
        sc = MFMA(kl0, qf[0],  sc);
        sc = MFMA(kl1, qf[1],  sc);
#pragma unroll
        for (int r = 0; r < 4; ++r) {
          const float d = sc[r] - mq;
          const float p = __expf(d);
          l1 += p;
          if (d > -16.f) {
            const int slot = atomicAdd(&pcnt[wave][c], 1);
            if (slot < 16) {
              plistP[wave][c][slot] = p;
              plistI[wave][c][slot] = (unsigned short)(g * 16 + quad * 4 + r);
            }
          }
        }
      }
    }
    if (cb < 15) {
      const int nb = buf ^ 1;
      *(bf16x8*)&SK[nb * 128 + sr][sphy]      = pA;
      *(bf16x8*)&SK[nb * 128 + sr + 64][sphy] = pB;
      __syncthreads();
      buf = nb;
    }
  }
  l1 += __shfl_xor(l1, 16, 64);
  l1 += __shfl_xor(l1, 32, 64);

  // ====================== phase C: finish (per-wave, tiny) ==================
  const float inv1 = 1.f / l1;
  float oc[16];
#pragma unroll
  for (int i = 0; i < 16; ++i) oc[i] = 0.f;
  float l2 = 0.f;
  const int n = min(pcnt[wave][c], 16);
  for (int j = 0; j < n; ++j) {
    const float a1 = plistP[wave][c][j] * inv1;  // attn1 in [0,1]
    const int  idx = plistI[wave][c][j];
    const float t1 = __expf(a1) - 1.0f;          // t-1
    l2 += t1;
    const bf16* vp = &v_p[(size_t)idx * HD + quad * 4];
#pragma unroll
    for (int dt = 0; dt < 4; ++dt) {
      bf16x4 v4 = *(const bf16x4*)&vp[dt * 16];
#pragma unroll
      for (int r = 0; r < 4; ++r) oc[dt * 4 + r] += t1 * (float)v4[r];
    }
  }

  const int b = bh >> 3, h = bh & 7;
  const float rcp = 1.f / (2048.f + l2);
  const float* vsp = Vs + bh * HD;
  bf16* orow = &O[((size_t)b * SEQ + q0 + c) * EMB + h * HD];
#pragma unroll
  for (int dt = 0; dt < 4; ++dt) {
    f32x4 vt4 = *(const f32x4*)&vsp[dt * 16 + quad * 4];
    bf16x4 ov;
#pragma unroll
    for (int r = 0; r < 4; ++r) ov[r] = (bf16)((oc[dt * 4 + r] + vt4[r]) * rcp);
    *(bf16x4*)&orow[dt * 16 + quad * 4] = ov;
  }
}

// ---------------------------------------------------------------------------
extern "C" void kernel_launch(void* const* d_in, const int* in_sizes, int n_in,
                              void* d_out, int out_size, void* d_ws, size_t ws_size,
                              hipStream_t stream) {
  const float* x    = (const float*)d_in[0];
  const float* Wqkv = (const float*)d_in[1];
  const float* bqkv = (const float*)d_in[2];
  const float* Wout = (const float*)d_in[3];
  const float* bout = (const float*)d_in[4];
  float* out = (float*)d_out;

  char* ws = (char*)d_ws;
  const size_t SZ = (size_t)32 * SEQ * HD * 2;  // 8 MB per array
  bf16* Qh  = (bf16*)(ws + 0 * SZ);
  bf16* Ql  = (bf16*)(ws + 1 * SZ);
  bf16* Kh  = (bf16*)(ws + 2 * SZ);
  bf16* Kl  = (bf16*)(ws + 3 * SZ);
  bf16* Vrm = (bf16*)(ws + 4 * SZ);
  bf16* O   = (bf16*)(ws + 5 * SZ);
  float* Vsum = (float*)(ws + 6 * SZ);          // +8KB: per-head V column sums

  gemm_qkv<<<dim3(128, 24), 256, 0, stream>>>(x, Wqkv, bqkv, Qh, Ql, Kh, Kl, Vrm);
  vsum_kernel<<<dim3(32), 256, 0, stream>>>(Vrm, Vsum);
  attn_kernel<<<dim3(32, SEQ / 128), 512, 0, stream>>>(Qh, Ql, Kh, Kl, Vrm, Vsum, O);
  gemm_out<<<dim3(128, 8), 256, 0, stream>>>(O, Wout, bout, out);
}

// Round 4
// 214.290 us; speedup vs baseline: 1.4551x; 1.1391x over previous
//
#include <hip/hip_runtime.h>

typedef __bf16 bf16;
typedef __attribute__((ext_vector_type(4))) __bf16 bf16x4;
typedef __attribute__((ext_vector_type(8))) __bf16 bf16x8;
typedef __attribute__((ext_vector_type(4))) float f32x4;

#define MFMA(A,B,C) __builtin_amdgcn_mfma_f32_16x16x32_bf16(A,B,C,0,0,0)

#define SEQ 2048
#define EMB 512
#define HD  64
#define SCALE 22.627416997969522f  // sqrt(512): scores are divided by E^-0.5
// Online-softmax seed: not -inf (fast-math folds inf constants to poison).
#define NEG_SEED -3.0e4f

// ---------------------------------------------------------------------------
// One-shot fp32 -> bf16 hi/lo conversion (x, W_qkv) and bf16 (W_out).
// Removes the per-block re-conversion VALU from both GEMMs (x tiles were
// converted 24x, W tiles 128x). Bitwise-identical rounding to the old code.
// ---------------------------------------------------------------------------
__global__ __launch_bounds__(256)
void convert_kernel(const float* __restrict__ x, const float* __restrict__ Wqkv,
                    const float* __restrict__ Wout,
                    bf16* __restrict__ Xh, bf16* __restrict__ Xl,
                    bf16* __restrict__ Wqh, bf16* __restrict__ Wql,
                    bf16* __restrict__ Wo) {
  const int NX = 8192 * 512 / 4;   // f32x4 chunks
  const int NW = 1536 * 512 / 4;
  const int NO = 512 * 512 / 4;
  const int stride = gridDim.x * 256;
  for (int i = blockIdx.x * 256 + threadIdx.x; i < NX + NW + NO; i += stride) {
    const float* src; bf16 *dh, *dl; int j; bool haslo;
    if (i < NX)           { src = x;    dh = Xh;  dl = Xl;  j = i;           haslo = true; }
    else if (i < NX + NW) { src = Wqkv; dh = Wqh; dl = Wql; j = i - NX;      haslo = true; }
    else                  { src = Wout; dh = Wo;  dl = Wo;  j = i - NX - NW; haslo = false; }
    f32x4 v = *(const f32x4*)&src[(size_t)j * 4];
    bf16x4 h4, l4;
#pragma unroll
    for (int r = 0; r < 4; ++r) {
      bf16 h = (bf16)v[r]; h4[r] = h; l4[r] = (bf16)(v[r] - (float)h);
    }
    *(bf16x4*)&dh[(size_t)j * 4] = h4;
    if (haslo) *(bf16x4*)&dl[(size_t)j * 4] = l4;
  }
}

// ---------------------------------------------------------------------------
// QKV projection: pure bf16 hi/lo GEMM on pre-converted inputs. XCD-stripe
// swizzle. LDS: linear [64][64] tiles + XOR-chunk swizzle (attn-proven,
// conflict-free) for both staging writes and fragment reads.
// ---------------------------------------------------------------------------
__global__ __launch_bounds__(256)
void gemm_qkv(const bf16* __restrict__ Xh, const bf16* __restrict__ Xl,
              const bf16* __restrict__ Wh, const bf16* __restrict__ Wl,
              const float* __restrict__ bias,
              bf16* __restrict__ Qh, bf16* __restrict__ Ql,
              bf16* __restrict__ Kh, bf16* __restrict__ Kl,
              bf16* __restrict__ Vrm) {
  __shared__ __align__(16) bf16 Ah[64][64], Al[64][64];
  __shared__ __align__(16) bf16 Bh[64][64], Bl[64][64];
  const int tid  = threadIdx.x;
  const int lane = tid & 63, wave = tid >> 6;
  const int lin = blockIdx.x + gridDim.x * blockIdx.y;
  const int xcd = lin & 7;
  const int w_  = lin >> 3;                  // 0..383
  const int m0 = ((w_ & 15) + xcd * 16) * 64;
  const int n0 = (w_ >> 4) * 64;
  const int wm = (wave >> 1) * 32, wn = (wave & 1) * 32;
  const int c = lane & 15, quad = lane >> 4;
  const int sr   = tid >> 3;                 // 0..31 staging row
  const int scol = (tid & 7) * 8;
  const int sphy = ((tid & 7) ^ (sr & 7)) * 8;   // (sr+32)&7 == sr&7

  const f32x4 zero = {0.f, 0.f, 0.f, 0.f};
  f32x4 acc[2][2];
  acc[0][0] = zero; acc[0][1] = zero; acc[1][0] = zero; acc[1][1] = zero;

  for (int k0 = 0; k0 < 512; k0 += 64) {
    *(bf16x8*)&Ah[sr][sphy]      = *(const bf16x8*)&Xh[(size_t)(m0 + sr     ) * 512 + k0 + scol];
    *(bf16x8*)&Ah[sr + 32][sphy] = *(const bf16x8*)&Xh[(size_t)(m0 + sr + 32) * 512 + k0 + scol];
    *(bf16x8*)&Al[sr][sphy]      = *(const bf16x8*)&Xl[(size_t)(m0 + sr     ) * 512 + k0 + scol];
    *(bf16x8*)&Al[sr + 32][sphy] = *(const bf16x8*)&Xl[(size_t)(m0 + sr + 32) * 512 + k0 + scol];
    *(bf16x8*)&Bh[sr][sphy]      = *(const bf16x8*)&Wh[(size_t)(n0 + sr     ) * 512 + k0 + scol];
    *(bf16x8*)&Bh[sr + 32][sphy] = *(const bf16x8*)&Wh[(size_t)(n0 + sr + 32) * 512 + k0 + scol];
    *(bf16x8*)&Bl[sr][sphy]      = *(const bf16x8*)&Wl[(size_t)(n0 + sr     ) * 512 + k0 + scol];
    *(bf16x8*)&Bl[sr + 32][sphy] = *(const bf16x8*)&Wl[(size_t)(n0 + sr + 32) * 512 + k0 + scol];
    __syncthreads();
#pragma unroll
    for (int ks = 0; ks < 64; ks += 32) {
      const int px = (((ks >> 3) + quad) ^ (c & 7)) * 8;
      bf16x8 ah0 = *(bf16x8*)&Ah[wm + c     ][px];
      bf16x8 ah1 = *(bf16x8*)&Ah[wm + 16 + c][px];
      bf16x8 al0 = *(bf16x8*)&Al[wm + c     ][px];
      bf16x8 al1 = *(bf16x8*)&Al[wm + 16 + c][px];
      bf16x8 bh0 = *(bf16x8*)&Bh[wn + c     ][px];
      bf16x8 bh1 = *(bf16x8*)&Bh[wn + 16 + c][px];
      bf16x8 bl0 = *(bf16x8*)&Bl[wn + c     ][px];
      bf16x8 bl1 = *(bf16x8*)&Bl[wn + 16 + c][px];
      acc[0][0] = MFMA(ah0, bh0, acc[0][0]);
      acc[0][0] = MFMA(al0, bh0, acc[0][0]);
      acc[0][0] = MFMA(ah0, bl0, acc[0][0]);
      acc[0][1] = MFMA(ah0, bh1, acc[0][1]);
      acc[0][1] = MFMA(al0, bh1, acc[0][1]);
      acc[0][1] = MFMA(ah0, bl1, acc[0][1]);
      acc[1][0] = MFMA(ah1, bh0, acc[1][0]);
      acc[1][0] = MFMA(al1, bh0, acc[1][0]);
      acc[1][0] = MFMA(ah1, bl0, acc[1][0]);
      acc[1][1] = MFMA(ah1, bh1, acc[1][1]);
      acc[1][1] = MFMA(al1, bh1, acc[1][1]);
      acc[1][1] = MFMA(ah1, bl1, acc[1][1]);
    }
    __syncthreads();
  }

#pragma unroll
  for (int mt = 0; mt < 2; ++mt) {
#pragma unroll
    for (int nt = 0; nt < 2; ++nt) {
      const int n = n0 + wn + nt * 16 + c;
      const float bv = bias[n];
#pragma unroll
      for (int r = 0; r < 4; ++r) {
        const int m = m0 + wm + mt * 16 + quad * 4 + r;
        float v = acc[mt][nt][r] + bv;
        const int h = n / 192, t = n % 192;
        const size_t bh = (size_t)((m >> 11) * 8 + h);
        const int s = m & 2047;
        if (t < 64) {
          float q = v * SCALE;
          bf16 hi = (bf16)q;
          float lo = q - (float)hi;
          size_t idx = (bh * SEQ + s) * HD + t;
          Qh[idx] = hi; Ql[idx] = (bf16)lo;
        } else if (t < 128) {
          bf16 hi = (bf16)v;
          float lo = v - (float)hi;
          size_t idx = (bh * SEQ + s) * HD + (t - 64);
          Kh[idx] = hi; Kl[idx] = (bf16)lo;
        } else {
          Vrm[(bh * SEQ + s) * HD + (t - 128)] = (bf16)v;
        }
      }
    }
  }
}

// ---------------------------------------------------------------------------
// Output projection: bf16 x bf16 (pre-converted Wo), fp32 out. Same XOR-swz.
// ---------------------------------------------------------------------------
__global__ __launch_bounds__(256)
void gemm_out(const bf16* __restrict__ A, const bf16* __restrict__ Wo,
              const float* __restrict__ bias, float* __restrict__ C) {
  __shared__ __align__(16) bf16 As[64][64];
  __shared__ __align__(16) bf16 Bs[64][64];
  const int tid  = threadIdx.x;
  const int lane = tid & 63, wave = tid >> 6;
  const int lin = blockIdx.x + gridDim.x * blockIdx.y;
  const int xcd = lin & 7;
  const int w_  = lin >> 3;                  // 0..127
  const int m0 = ((w_ & 15) + xcd * 16) * 64;
  const int n0 = (w_ >> 4) * 64;
  const int wm = (wave >> 1) * 32, wn = (wave & 1) * 32;
  const int c = lane & 15, quad = lane >> 4;
  const int sr   = tid >> 3;
  const int scol = (tid & 7) * 8;
  const int sphy = ((tid & 7) ^ (sr & 7)) * 8;

  const f32x4 zero = {0.f, 0.f, 0.f, 0.f};
  f32x4 acc[2][2];
  acc[0][0] = zero; acc[0][1] = zero; acc[1][0] = zero; acc[1][1] = zero;

  for (int k0 = 0; k0 < 512; k0 += 64) {
    *(bf16x8*)&As[sr][sphy]      = *(const bf16x8*)&A [(size_t)(m0 + sr     ) * 512 + k0 + scol];
    *(bf16x8*)&As[sr + 32][sphy] = *(const bf16x8*)&A [(size_t)(m0 + sr + 32) * 512 + k0 + scol];
    *(bf16x8*)&Bs[sr][sphy]      = *(const bf16x8*)&Wo[(size_t)(n0 + sr     ) * 512 + k0 + scol];
    *(bf16x8*)&Bs[sr + 32][sphy] = *(const bf16x8*)&Wo[(size_t)(n0 + sr + 32) * 512 + k0 + scol];
    __syncthreads();
#pragma unroll
    for (int ks = 0; ks < 64; ks += 32) {
      const int px = (((ks >> 3) + quad) ^ (c & 7)) * 8;
      bf16x8 a0 = *(bf16x8*)&As[wm + c     ][px];
      bf16x8 a1 = *(bf16x8*)&As[wm + 16 + c][px];
      bf16x8 b0 = *(bf16x8*)&Bs[wn + c     ][px];
      bf16x8 b1 = *(bf16x8*)&Bs[wn + 16 + c][px];
      acc[0][0] = MFMA(a0, b0, acc[0][0]);
      acc[0][1] = MFMA(a0, b1, acc[0][1]);
      acc[1][0] = MFMA(a1, b0, acc[1][0]);
      acc[1][1] = MFMA(a1, b1, acc[1][1]);
    }
    __syncthreads();
  }

#pragma unroll
  for (int mt = 0; mt < 2; ++mt) {
#pragma unroll
    for (int nt = 0; nt < 2; ++nt) {
      const int n = n0 + wn + nt * 16 + c;
      const float bv = bias[n];
#pragma unroll
      for (int r = 0; r < 4; ++r) {
        const int m = m0 + wm + mt * 16 + quad * 4 + r;
        C[(size_t)m * 512 + n] = acc[mt][nt][r] + bv;
      }
    }
  }
}

// ---------------------------------------------------------------------------
// Per-head V column partial sums: Vp[pc][bh][d] = sum_{s in chunk pc} V[s][d].
// 256 blocks (8 chunks x 32 heads) -> full GPU; attn sums the 8 partials.
// ---------------------------------------------------------------------------
__global__ __launch_bounds__(256)
void vsum_kernel(const bf16* __restrict__ Vrm, float* __restrict__ Vp) {
  __shared__ float red[32][64];
  const int pc = blockIdx.x >> 5;
  const int bh = blockIdx.x & 31;
  const bf16* p = Vrm + ((size_t)bh * SEQ + pc * 256) * HD;
  const int g  = threadIdx.x >> 3;
  const int dc = (threadIdx.x & 7) * 8;
  float s[8] = {0.f,0.f,0.f,0.f,0.f,0.f,0.f,0.f};
  for (int s0 = g; s0 < 256; s0 += 32) {
    bf16x8 v = *(const bf16x8*)&p[(size_t)s0 * HD + dc];
#pragma unroll
    for (int j = 0; j < 8; ++j) s[j] += (float)v[j];
  }
#pragma unroll
  for (int j = 0; j < 8; ++j) red[g][dc + j] = s[j];
  __syncthreads();
  if (threadIdx.x < 64) {
    float a = 0.f;
#pragma unroll
    for (int g2 = 0; g2 < 32; ++g2) a += red[g2][threadIdx.x];
    Vp[(size_t)(pc * 32 + bh) * 64 + threadIdx.x] = a;
  }
}

// ---------------------------------------------------------------------------
// Attention, double softmax, shift-invariant 3-phase form (round-3, 83.8us).
// Unchanged except the epilogue sums 8 Vtot partials.
// ---------------------------------------------------------------------------
__global__ __launch_bounds__(512, 4)
void attn_kernel(const bf16* __restrict__ Qh, const bf16* __restrict__ Ql,
                 const bf16* __restrict__ Kh, const bf16* __restrict__ Kl,
                 const bf16* __restrict__ Vrm, const float* __restrict__ Vp,
                 bf16* __restrict__ O) {
  __shared__ __align__(16) char pool[32768];     // Kh stage [2][128][64] bf16
  __shared__ unsigned char cms8[8][128][16];     // per-wave tile-max (s~/8+128)
  __shared__ float plistP[8][16][16];            // per-query p list
  __shared__ unsigned short plistI[8][16][16];   // per-query key-idx list
  __shared__ int pcnt[8][16];
  bf16 (*SK)[64] = (bf16(*)[64])pool;

  const int tid  = threadIdx.x;
  const int lane = tid & 63, wave = tid >> 6;
  const int c = lane & 15, quad = lane >> 4;
  const int bh = blockIdx.x;
  const int q0 = blockIdx.y * 128 + wave * 16;
  const size_t hoff = (size_t)bh * SEQ * HD;
  const bf16* qh_p = Qh + hoff;
  const bf16* ql_p = Ql + hoff;
  const bf16* kh_p = Kh + hoff;
  const bf16* kl_p = Kl + hoff;
  const bf16* v_p  = Vrm + hoff;
  const f32x4 zero = {0.f, 0.f, 0.f, 0.f};

  const int sr   = tid >> 3;                     // 0..63 staging row
  const int scol = (tid & 7) * 8;
  const int sphy = ((tid & 7) ^ (sr & 7)) * 8;
  const int pc0  = ((0 + quad) ^ (c & 7)) * 8;
  const int pc1  = ((4 + quad) ^ (c & 7)) * 8;

  bf16x8 qf[2], qlf[2];
#pragma unroll
  for (int t = 0; t < 2; ++t) {
    size_t off = (size_t)(q0 + c) * HD + t * 32 + quad * 8;
    qf[t]  = *(const bf16x8*)&qh_p[off];
    qlf[t] = *(const bf16x8*)&ql_p[off];
  }

  // ====================== phase SCAN: hi-only s~ ======================
  bf16x8 pA = *(const bf16x8*)&kh_p[(size_t)sr * HD + scol];
  bf16x8 pB = *(const bf16x8*)&kh_p[(size_t)(sr + 64) * HD + scol];
  *(bf16x8*)&SK[sr][sphy]      = pA;
  *(bf16x8*)&SK[sr + 64][sphy] = pB;
  __syncthreads();
  int buf = 0;
  float mqL = NEG_SEED;
  for (int cs = 0; cs < 16; ++cs) {
    if (cs < 15) {
      const size_t k0 = (size_t)(cs + 1) * 128;
      pA = *(const bf16x8*)&kh_p[(k0 + sr) * HD + scol];
      pB = *(const bf16x8*)&kh_p[(k0 + sr + 64) * HD + scol];
    }
#pragma unroll
    for (int t = 0; t < 8; ++t) {
      bf16x8 k0 = *(bf16x8*)&SK[buf * 128 + t * 16 + c][pc0];
      bf16x8 k1 = *(bf16x8*)&SK[buf * 128 + t * 16 + c][pc1];
      f32x4 sc = MFMA(k0, qf[0], zero);
      sc = MFMA(k1, qf[1], sc);
      float cm = fmaxf(fmaxf(sc[0], sc[1]), fmaxf(sc[2], sc[3]));
      mqL = fmaxf(mqL, cm);
      float c2 = fmaxf(cm, __shfl_xor(cm, 16, 64));
      c2 = fmaxf(c2, __shfl_xor(c2, 32, 64));
      if (quad == 0) {
        int qv = (int)(c2 * 0.125f + 128.5f);
        qv = qv < 0 ? 0 : (qv > 255 ? 255 : qv);
        cms8[wave][cs * 8 + t][c] = (unsigned char)qv;
      }
    }
    if (cs < 15) {
      const int nb = buf ^ 1;
      *(bf16x8*)&SK[nb * 128 + sr][sphy]      = pA;
      *(bf16x8*)&SK[nb * 128 + sr + 64][sphy] = pB;
      __syncthreads();
      buf = nb;
    }
  }
  __syncthreads();   // all waves done reading SK before phase-B restaging
  float mq = fmaxf(mqL, __shfl_xor(mqL, 16, 64));
  mq = fmaxf(mq, __shfl_xor(mq, 32, 64));

  // ====================== phase B: exact scores, gated ======================
  if (lane < 16) pcnt[wave][lane] = 0;   // same-wave use only
  pA = *(const bf16x8*)&kh_p[(size_t)sr * HD + scol];
  pB = *(const bf16x8*)&kh_p[(size_t)(sr + 64) * HD + scol];
  *(bf16x8*)&SK[sr][sphy]      = pA;
  *(bf16x8*)&SK[sr + 64][sphy] = pB;
  __syncthreads();
  buf = 0;
  float l1 = 0.f;
  for (int cb = 0; cb < 16; ++cb) {
    if (cb < 15) {
      const size_t k0 = (size_t)(cb + 1) * 128;
      pA = *(const bf16x8*)&kh_p[(k0 + sr) * HD + scol];
      pB = *(const bf16x8*)&kh_p[(k0 + sr + 64) * HD + scol];
    }
#pragma unroll
    for (int t = 0; t < 8; ++t) {
      const int g = cb * 8 + t;
      const float cv = (float)((int)cms8[wave][g][c] - 128) * 8.0f;
      if (__any(cv > mq - 28.f)) {
        bf16x8 kh0 = *(bf16x8*)&SK[buf * 128 + t * 16 + c][pc0];
        bf16x8 kh1 = *(bf16x8*)&SK[buf * 128 + t * 16 + c][pc1];
        const size_t krow = (size_t)(g * 16 + c) * HD;
        bf16x8 kl0 = *(const bf16x8*)&kl_p[krow + quad * 8];
        bf16x8 kl1 = *(const bf16x8*)&kl_p[krow + 32 + quad * 8];
        f32x4 sc = MFMA(kh0, qf[0], zero);   // kl terms last: global-load
        sc = MFMA(kh0, qlf[0], sc);          // latency hides behind kh MFMAs
        sc = MFMA(kh1, qf[1],  sc);
        sc = MFMA(kh1, qlf[1], sc);
        sc = MFMA(kl0, qf[0],  sc);
        sc = MFMA(kl1, qf[1],  sc);
#pragma unroll
        for (int r = 0; r < 4; ++r) {
          const float d = sc[r] - mq;
          const float p = __expf(d);
          l1 += p;
          if (d > -16.f) {
            const int slot = atomicAdd(&pcnt[wave][c], 1);
            if (slot < 16) {
              plistP[wave][c][slot] = p;
              plistI[wave][c][slot] = (unsigned short)(g * 16 + quad * 4 + r);
            }
          }
        }
      }
    }
    if (cb < 15) {
      const int nb = buf ^ 1;
      *(bf16x8*)&SK[nb * 128 + sr][sphy]      = pA;
      *(bf16x8*)&SK[nb * 128 + sr + 64][sphy] = pB;
      __syncthreads();
      buf = nb;
    }
  }
  l1 += __shfl_xor(l1, 16, 64);
  l1 += __shfl_xor(l1, 32, 64);

  // ====================== phase C: finish (per-wave, tiny) ==================
  const float inv1 = 1.f / l1;
  float oc[16];
#pragma unroll
  for (int i = 0; i < 16; ++i) oc[i] = 0.f;
  float l2 = 0.f;
  const int n = min(pcnt[wave][c], 16);
  for (int j = 0; j < n; ++j) {
    const float a1 = plistP[wave][c][j] * inv1;  // attn1 in [0,1]
    const int  idx = plistI[wave][c][j];
    const float t1 = __expf(a1) - 1.0f;          // t-1
    l2 += t1;
    const bf16* vp = &v_p[(size_t)idx * HD + quad * 4];
#pragma unroll
    for (int dt = 0; dt < 4; ++dt) {
      bf16x4 v4 = *(const bf16x4*)&vp[dt * 16];
#pragma unroll
      for (int r = 0; r < 4; ++r) oc[dt * 4 + r] += t1 * (float)v4[r];
    }
  }

  const int b = bh >> 3, h = bh & 7;
  const float rcp = 1.f / (2048.f + l2);
  const float* vpp = Vp + (size_t)bh * HD;       // partial chunks stride 32*64
  bf16* orow = &O[((size_t)b * SEQ + q0 + c) * EMB + h * HD];
#pragma unroll
  for (int dt = 0; dt < 4; ++dt) {
    f32x4 vt4 = zero;
#pragma unroll
    for (int pc = 0; pc < 8; ++pc)
      vt4 += *(const f32x4*)&vpp[(size_t)pc * 32 * 64 + dt * 16 + quad * 4];
    bf16x4 ov;
#pragma unroll
    for (int r = 0; r < 4; ++r) ov[r] = (bf16)((oc[dt * 4 + r] + vt4[r]) * rcp);
    *(bf16x4*)&orow[dt * 16 + quad * 4] = ov;
  }
}

// ---------------------------------------------------------------------------
extern "C" void kernel_launch(void* const* d_in, const int* in_sizes, int n_in,
                              void* d_out, int out_size, void* d_ws, size_t ws_size,
                              hipStream_t stream) {
  const float* x    = (const float*)d_in[0];
  const float* Wqkv = (const float*)d_in[1];
  const float* bqkv = (const float*)d_in[2];
  const float* Wout = (const float*)d_in[3];
  const float* bout = (const float*)d_in[4];
  float* out = (float*)d_out;

  char* ws = (char*)d_ws;
  const size_t SZ = (size_t)32 * SEQ * HD * 2;  // 8 MiB per array
  bf16* Qh  = (bf16*)(ws + 0 * SZ);
  bf16* Ql  = (bf16*)(ws + 1 * SZ);
  bf16* Kh  = (bf16*)(ws + 2 * SZ);
  bf16* Kl  = (bf16*)(ws + 3 * SZ);
  bf16* Vrm = (bf16*)(ws + 4 * SZ);
  bf16* XhO = (bf16*)(ws + 5 * SZ);  // Xh during proj; overwritten by O in attn
  bf16* Xl  = (bf16*)(ws + 6 * SZ);
  bf16* Wqh = (bf16*)(ws + 7 * SZ);
  bf16* Wql = (bf16*)(ws + 7 * SZ + 0x180000);
  bf16* Wo  = (bf16*)(ws + 7 * SZ + 0x300000);
  float* Vp = (float*)(ws + 7 * SZ + 0x380000);  // 8x32x64 f32 partials

  convert_kernel<<<dim3(2048), 256, 0, stream>>>(x, Wqkv, Wout, XhO, Xl, Wqh, Wql, Wo);
  gemm_qkv<<<dim3(128, 24), 256, 0, stream>>>(XhO, Xl, Wqh, Wql, bqkv, Qh, Ql, Kh, Kl, Vrm);
  vsum_kernel<<<dim3(256), 256, 0, stream>>>(Vrm, Vp);
  attn_kernel<<<dim3(32, SEQ / 128), 512, 0, stream>>>(Qh, Ql, Kh, Kl, Vrm, Vp, XhO);
  gemm_out<<<dim3(128, 8), 256, 0, stream>>>(XhO, Wo, bout, out);
}